// Round 5
// baseline (169.869 us; speedup 1.0000x reference)
//
#include <hip/hip_runtime.h>
#include <hip/hip_bf16.h>
#include <stdint.h>

// scores[b,q,k] = dot(Q[b,q,:],K[b,k,:]) / (max(|Qrow|,eps)*max(|Krow|,eps)); mask==0 -> -1e9
// B=4, Sq=Sk=2048, D=1024, fp32 in/out.
//
// R5: double-buffered BK=32 (same 32KB LDS as R4 single-buffer BK=64) so the
//     global_load_lds DMA for tile k+1 overlaps compute of tile k instead of
//     being drained by an immediately-following barrier (R4's exposed-latency stall).
//     Swizzle f(r)=(r>>1)&3 keeps fragment ds_read_b128 at 2-way banks (free).
//     Epilogue operand loads hoisted above K-loop; output stores nontemporal.
// Fallback (ws too small): R1 single-kernel bf16, LDK=40.

constexpr int B_  = 4;
constexpr int SQ  = 2048;
constexpr int SK  = 2048;
constexpr int D_  = 1024;
constexpr int BM  = 128;
constexpr int BN  = 128;
constexpr int BK  = 32;    // 64 B rows = 4 x 16B chunks
constexpr int NIT = D_ / BK;  // 32

typedef __attribute__((ext_vector_type(8))) short    short8;
typedef __attribute__((ext_vector_type(4))) float    f32x4;
typedef __attribute__((ext_vector_type(4))) unsigned uint4v;
typedef unsigned int u32;

__device__ inline unsigned pack_bf16(float lo, float hi) {
  union { float f; unsigned u; } a, b;
  a.f = lo; b.f = hi;
  return __builtin_amdgcn_perm(b.u, a.u, 0x07060302u);
}

__device__ inline void async_ld16(const void* g, void* l) {
  __builtin_amdgcn_global_load_lds((const __attribute__((address_space(1))) u32*)g,
                                   (__attribute__((address_space(3))) u32*)l, 16, 0, 0);
}

// ---------------- Pass 1: convert + norms ----------------
constexpr int ROWS_Q = B_ * SQ;           // 8192
constexpr int ROWS_T = B_ * (SQ + SK);    // 16384

__global__ __launch_bounds__(256) void convert_norm(
    const float* __restrict__ Q, const float* __restrict__ Km,
    unsigned short* __restrict__ Qb, unsigned short* __restrict__ Kb,
    float* __restrict__ invQ, float* __restrict__ invK)
{
  const int row  = blockIdx.x * 4 + (threadIdx.x >> 6);
  const int lane = threadIdx.x & 63;

  const float* src; unsigned short* dst; float* inv;
  if (row < ROWS_Q) {
    src = Q  + (size_t)row * D_;
    dst = Qb + (size_t)row * D_;
    inv = invQ + row;
  } else {
    int r = row - ROWS_Q;
    src = Km + (size_t)r * D_;
    dst = Kb + (size_t)r * D_;
    inv = invK + r;
  }

  const f32x4* s4 = (const f32x4*)(src + lane * 16);
  f32x4 v[4];
  #pragma unroll
  for (int i = 0; i < 4; ++i) v[i] = s4[i];

  float ss = 0.0f;
  unsigned p[8];
  #pragma unroll
  for (int i = 0; i < 4; ++i) {
    p[2*i]   = pack_bf16(v[i].x, v[i].y);
    p[2*i+1] = pack_bf16(v[i].z, v[i].w);
    ss += v[i].x*v[i].x + v[i].y*v[i].y + v[i].z*v[i].z + v[i].w*v[i].w;
  }
  uint4v w0 = {p[0], p[1], p[2], p[3]};
  uint4v w1 = {p[4], p[5], p[6], p[7]};
  uint4v* d4 = (uint4v*)(dst + lane * 16);
  d4[0] = w0; d4[1] = w1;

  #pragma unroll
  for (int off = 32; off > 0; off >>= 1) ss += __shfl_xor(ss, off);
  if (lane == 0) *inv = 1.0f / fmaxf(sqrtf(ss), 1e-8f);
}

// ---------------- Pass 2: bf16 GEMM, BK=32 double-buffered, swizzled ----------------
// LDS row r (64 B = 4 x 16B chunks): position p holds global chunk p ^ f(r), f(r)=(r>>1)&3.
// Staging: one async_ld16 = 16 rows x 64 B; lane -> row lane>>2, pos lane&3,
//          fetch global chunk (lane&3) ^ ((lane>>3)&3).
// Fragment read (16 lanes, fixed lq): bank = (r&1)*16 + (lq^f(r))*4 -> 32 banks 2-way (free).
__global__ __launch_bounds__(256, 2) void ca_gemm_bf(
    const unsigned short* __restrict__ Qb,   // [B][SQ][D] bf16
    const unsigned short* __restrict__ Kb,   // [B][SK][D] bf16
    const float* __restrict__ invQ,
    const float* __restrict__ invK,
    const int*   __restrict__ mask,
    float*       __restrict__ out)
{
  __shared__ __align__(16) unsigned short As[2][BM * BK];   // 2 x 8 KB
  __shared__ __align__(16) unsigned short Bs[2][BN * BK];   // 2 x 8 KB

  const int tid  = threadIdx.x;
  const int lane = tid & 63;
  const int w    = tid >> 6;
  const int b    = blockIdx.z;
  const int tm0  = blockIdx.y * BM;
  const int tn0  = blockIdx.x * BN;

  const int srow   = lane >> 2;                       // 0..15
  const int gchunk = (lane & 3) ^ ((lane >> 3) & 3);  // swizzled global 16B chunk

  const char* qrow = (const char*)(Qb + ((size_t)b * SQ + tm0 + w * 32 + srow) * D_) + gchunk * 16;
  const char* krow = (const char*)(Kb + ((size_t)b * SK + tn0 + w * 32 + srow) * D_) + gchunk * 16;
  const size_t rstep16 = (size_t)16 * D_ * 2;   // 16 rows in bytes

  unsigned short* ldsA0[2] = { &As[0][(w * 32) * BK], &As[1][(w * 32) * BK] };
  unsigned short* ldsB0[2] = { &Bs[0][(w * 32) * BK], &Bs[1][(w * 32) * BK] };

  f32x4 zero4 = {0.0f, 0.0f, 0.0f, 0.0f};
  f32x4 acc[4][4];
  #pragma unroll
  for (int i = 0; i < 4; ++i)
    #pragma unroll
    for (int j = 0; j < 4; ++j) acc[i][j] = zero4;

  const int wm = (w >> 1) * 64;
  const int wn = (w & 1) * 64;
  const int lr = lane & 15;
  const int lq = lane >> 4;

  // Hoist epilogue operands above the K-loop (drained at first barrier, live in regs).
  int   mk[4]; float ib[4]; float ia[4][4];
  #pragma unroll
  for (int tn = 0; tn < 4; ++tn) {
    const int gc = tn0 + wn + tn * 16 + lr;
    mk[tn] = mask[b * SK + gc];
    ib[tn] = invK[b * SK + gc];
  }
  #pragma unroll
  for (int tm = 0; tm < 4; ++tm) {
    const int lrow = wm + tm * 16 + lq * 4;
    #pragma unroll
    for (int r = 0; r < 4; ++r) ia[tm][r] = invQ[b * SQ + tm0 + lrow + r];
  }

  auto stage = [&](int buf, int k0) {
    const size_t kb = (size_t)k0 * 2;
    async_ld16(qrow + kb,           ldsA0[buf]);
    async_ld16(qrow + kb + rstep16, ldsA0[buf] + 16 * BK);
    async_ld16(krow + kb,           ldsB0[buf]);
    async_ld16(krow + kb + rstep16, ldsB0[buf] + 16 * BK);
  };

  auto compute = [&](const unsigned short* Ac, const unsigned short* Bc) {
    short8 af[4], bf[4];
    #pragma unroll
    for (int t = 0; t < 4; ++t) {
      const int r = wm + t * 16 + lr;
      af[t] = *(const short8*)&Ac[(size_t)r * BK + (size_t)((lq ^ ((r >> 1) & 3)) * 8)];
    }
    #pragma unroll
    for (int t = 0; t < 4; ++t) {
      const int r = wn + t * 16 + lr;
      bf[t] = *(const short8*)&Bc[(size_t)r * BK + (size_t)((lq ^ ((r >> 1) & 3)) * 8)];
    }
    #pragma unroll
    for (int i = 0; i < 4; ++i)
      #pragma unroll
      for (int j = 0; j < 4; ++j)
        acc[i][j] = __builtin_amdgcn_mfma_f32_16x16x32_bf16(af[i], bf[j], acc[i][j], 0, 0, 0);
  };

  stage(0, 0);
  for (int it = 0; it < NIT; it += 2) {
    __syncthreads();                              // tile it ready (DMA overlapped prev compute)
    if (it + 1 < NIT) stage(1, (it + 1) * BK);    // prefetch next into other buffer
    compute(As[0], Bs[0]);
    __syncthreads();                              // tile it+1 ready
    if (it + 2 < NIT) stage(0, (it + 2) * BK);
    compute(As[1], Bs[1]);
  }

  // Epilogue: C/D col=lane&15, row=(lane>>4)*4+reg. Nontemporal (output never re-read).
  #pragma unroll
  for (int tn = 0; tn < 4; ++tn) {
    const int gc = tn0 + wn + tn * 16 + lr;
    #pragma unroll
    for (int tm = 0; tm < 4; ++tm) {
      const int lrow = wm + tm * 16 + lq * 4;
      #pragma unroll
      for (int r = 0; r < 4; ++r) {
        float v = mk[tn] ? acc[tm][tn][r] * ia[tm][r] * ib[tn] : -1000000000.0f;
        __builtin_nontemporal_store(v, &out[((size_t)b * SQ + tm0 + lrow + r) * SK + gc]);
      }
    }
  }
}

// ---------------- Fallback: single-kernel bf16, LDK=40 ----------------
constexpr int LDK = 40;

__global__ __launch_bounds__(256, 2) void ca_gemm(
    const float* __restrict__ Q, const float* __restrict__ Km,
    const int* __restrict__ mask, float* __restrict__ out)
{
  __shared__ __align__(16) short As[BM * LDK];
  __shared__ __align__(16) short Bs[BN * LDK];
  __shared__ float ssA_part[256];
  __shared__ float ssB_part[256];
  __shared__ float invA[BM];
  __shared__ float invB[BN];

  const int tid  = threadIdx.x;
  const int lane = tid & 63;
  const int w    = tid >> 6;
  const int b    = blockIdx.z;
  const int tm0  = blockIdx.y * BM;
  const int tn0  = blockIdx.x * BN;

  const int ra = tid >> 1;
  const int ka = (tid & 1) * 16;

  const float* qp = Q  + ((size_t)b * SQ + tm0 + ra) * D_ + ka;
  const float* kp = Km + ((size_t)b * SK + tn0 + ra) * D_ + ka;

  f32x4 zero4 = {0.0f, 0.0f, 0.0f, 0.0f};
  f32x4 acc[4][4];
  #pragma unroll
  for (int i = 0; i < 4; ++i)
    #pragma unroll
    for (int j = 0; j < 4; ++j) acc[i][j] = zero4;

  float ssA = 0.0f, ssB = 0.0f;

  const int wm = (w >> 1) * 64;
  const int wn = (w & 1) * 64;
  const int lr = lane & 15;
  const int lq = lane >> 4;

  short* aw = &As[ra * LDK + ka];
  short* bw = &Bs[ra * LDK + ka];

  for (int k0 = 0; k0 < D_; k0 += 32) {
    f32x4 av[4], bv[4];
    #pragma unroll
    for (int i = 0; i < 4; ++i) av[i] = *(const f32x4*)(qp + 4 * i);
    #pragma unroll
    for (int i = 0; i < 4; ++i) bv[i] = *(const f32x4*)(kp + 4 * i);
    qp += 32; kp += 32;

    unsigned pa[8], pb[8];
    #pragma unroll
    for (int i = 0; i < 4; ++i) {
      pa[2*i]   = pack_bf16(av[i].x, av[i].y);
      pa[2*i+1] = pack_bf16(av[i].z, av[i].w);
      pb[2*i]   = pack_bf16(bv[i].x, bv[i].y);
      pb[2*i+1] = pack_bf16(bv[i].z, bv[i].w);
      ssA += av[i].x*av[i].x + av[i].y*av[i].y + av[i].z*av[i].z + av[i].w*av[i].w;
      ssB += bv[i].x*bv[i].x + bv[i].y*bv[i].y + bv[i].z*bv[i].z + bv[i].w*bv[i].w;
    }

    __syncthreads();
    {
      uint4v wa0 = {pa[0], pa[1], pa[2], pa[3]};
      uint4v wa1 = {pa[4], pa[5], pa[6], pa[7]};
      uint4v wb0 = {pb[0], pb[1], pb[2], pb[3]};
      uint4v wb1 = {pb[4], pb[5], pb[6], pb[7]};
      *(uint4v*)(aw)     = wa0;
      *(uint4v*)(aw + 8) = wa1;
      *(uint4v*)(bw)     = wb0;
      *(uint4v*)(bw + 8) = wb1;
    }
    __syncthreads();

    short8 af[4], bf[4];
    #pragma unroll
    for (int t = 0; t < 4; ++t)
      af[t] = *(const short8*)&As[(wm + t * 16 + lr) * LDK + lq * 8];
    #pragma unroll
    for (int t = 0; t < 4; ++t)
      bf[t] = *(const short8*)&Bs[(wn + t * 16 + lr) * LDK + lq * 8];

    #pragma unroll
    for (int i = 0; i < 4; ++i)
      #pragma unroll
      for (int j = 0; j < 4; ++j)
        acc[i][j] = __builtin_amdgcn_mfma_f32_16x16x32_bf16(af[i], bf[j], acc[i][j], 0, 0, 0);
  }

  ssA_part[tid] = ssA;
  ssB_part[tid] = ssB;
  __syncthreads();
  if (tid < BM) {
    float s = ssA_part[2 * tid] + ssA_part[2 * tid + 1];
    invA[tid] = 1.0f / fmaxf(sqrtf(s), 1e-8f);
  } else {
    int r = tid - BM;
    float s = ssB_part[2 * r] + ssB_part[2 * r + 1];
    invB[r] = 1.0f / fmaxf(sqrtf(s), 1e-8f);
  }
  __syncthreads();

  #pragma unroll
  for (int tn = 0; tn < 4; ++tn) {
    const int lc = wn + tn * 16 + lr;
    const int gc = tn0 + lc;
    const int mk = mask[b * SK + gc];
    const float ibv = invB[lc];
    #pragma unroll
    for (int tm = 0; tm < 4; ++tm) {
      const int lrow = wm + tm * 16 + lq * 4;
      #pragma unroll
      for (int r = 0; r < 4; ++r) {
        float v = mk ? acc[tm][tn][r] * invA[lrow + r] * ibv : -1000000000.0f;
        out[((size_t)b * SQ + tm0 + lrow + r) * SK + gc] = v;
      }
    }
  }
}

extern "C" void kernel_launch(void* const* d_in, const int* in_sizes, int n_in,
                              void* d_out, int out_size, void* d_ws, size_t ws_size,
                              hipStream_t stream) {
  const float* Q    = (const float*)d_in[0];
  const float* Km   = (const float*)d_in[1];
  const int*   mask = (const int*)d_in[2];
  float*       out  = (float*)d_out;

  const size_t nQ   = (size_t)B_ * SQ * D_;        // elements
  const size_t nK   = (size_t)B_ * SK * D_;
  const size_t need = (nQ + nK) * 2 + (size_t)B_ * (SQ + SK) * 4;
  if (ws_size >= need) {
    unsigned short* Qb = (unsigned short*)d_ws;
    unsigned short* Kb = Qb + nQ;
    float*          iQ = (float*)(Kb + nK);
    float*          iK = iQ + (size_t)B_ * SQ;
    convert_norm<<<ROWS_T / 4, 256, 0, stream>>>(Q, Km, Qb, Kb, iQ, iK);
    dim3 grid(SK / BN, SQ / BM, B_);
    ca_gemm_bf<<<grid, dim3(256), 0, stream>>>(Qb, Kb, iQ, iK, mask, out);
  } else {
    dim3 grid(SK / BN, SQ / BM, B_);
    ca_gemm<<<grid, dim3(256), 0, stream>>>(Q, Km, mask, out);
  }
}

// Round 6
// 159.747 us; speedup vs baseline: 1.0634x; 1.0634x over previous
//
#include <hip/hip_runtime.h>
#include <hip/hip_bf16.h>
#include <stdint.h>

// scores[b,q,k] = dot(Q[b,q,:],K[b,k,:]) / (max(|Qrow|,eps)*max(|Krow|,eps)); mask==0 -> -1e9
// B=4, Sq=Sk=2048, D=1024, fp32 in/out.
//
// R6: R4 structure exactly (BK=64 single-buffer, global_load_lds w=16, XOR swizzle,
//     conflicts=0, gemm 56us) with the MFMA swapped 16x16x32 -> 32x32x16
//     (2382 vs 2075 TF ubench; per-iter MFMA issue 155->129 cyc/wave, same LDS traffic).
//     R5's dbuf + hoist + nt stores reverted (regressed 56->68.5us).
// Pass 1: fp32 -> bf16 in d_ws + row inv-norms.
// Fallback (ws too small): R1 single-kernel bf16, LDK=40.

constexpr int B_  = 4;
constexpr int SQ  = 2048;
constexpr int SK  = 2048;
constexpr int D_  = 1024;
constexpr int BM  = 128;
constexpr int BN  = 128;
constexpr int BK  = 64;    // bf16 K-tile: 128 B rows = 8 x 16B chunks

typedef __attribute__((ext_vector_type(8)))  short    short8;
typedef __attribute__((ext_vector_type(4)))  float    f32x4;
typedef __attribute__((ext_vector_type(16))) float    f32x16;
typedef __attribute__((ext_vector_type(4)))  unsigned uint4v;
typedef unsigned int u32;

__device__ inline unsigned pack_bf16(float lo, float hi) {
  union { float f; unsigned u; } a, b;
  a.f = lo; b.f = hi;
  return __builtin_amdgcn_perm(b.u, a.u, 0x07060302u);
}

__device__ inline void async_ld16(const void* g, void* l) {
  __builtin_amdgcn_global_load_lds((const __attribute__((address_space(1))) u32*)g,
                                   (__attribute__((address_space(3))) u32*)l, 16, 0, 0);
}

// ---------------- Pass 1: convert + norms ----------------
constexpr int ROWS_Q = B_ * SQ;           // 8192
constexpr int ROWS_T = B_ * (SQ + SK);    // 16384

__global__ __launch_bounds__(256) void convert_norm(
    const float* __restrict__ Q, const float* __restrict__ Km,
    unsigned short* __restrict__ Qb, unsigned short* __restrict__ Kb,
    float* __restrict__ invQ, float* __restrict__ invK)
{
  const int row  = blockIdx.x * 4 + (threadIdx.x >> 6);
  const int lane = threadIdx.x & 63;

  const float* src; unsigned short* dst; float* inv;
  if (row < ROWS_Q) {
    src = Q  + (size_t)row * D_;
    dst = Qb + (size_t)row * D_;
    inv = invQ + row;
  } else {
    int r = row - ROWS_Q;
    src = Km + (size_t)r * D_;
    dst = Kb + (size_t)r * D_;
    inv = invK + r;
  }

  const f32x4* s4 = (const f32x4*)(src + lane * 16);
  f32x4 v[4];
  #pragma unroll
  for (int i = 0; i < 4; ++i) v[i] = s4[i];

  float ss = 0.0f;
  unsigned p[8];
  #pragma unroll
  for (int i = 0; i < 4; ++i) {
    p[2*i]   = pack_bf16(v[i].x, v[i].y);
    p[2*i+1] = pack_bf16(v[i].z, v[i].w);
    ss += v[i].x*v[i].x + v[i].y*v[i].y + v[i].z*v[i].z + v[i].w*v[i].w;
  }
  uint4v w0 = {p[0], p[1], p[2], p[3]};
  uint4v w1 = {p[4], p[5], p[6], p[7]};
  uint4v* d4 = (uint4v*)(dst + lane * 16);
  d4[0] = w0; d4[1] = w1;

  #pragma unroll
  for (int off = 32; off > 0; off >>= 1) ss += __shfl_xor(ss, off);
  if (lane == 0) *inv = 1.0f / fmaxf(sqrtf(ss), 1e-8f);
}

// ---------------- Pass 2: bf16 GEMM, BK=64, swizzled LDS, 32x32x16 MFMA ----------------
// LDS row r (128 B = 8 x 16B chunks): position p holds global chunk p ^ (r&7).
// Staging (unchanged from R4): one async_ld16 = 8 rows x 128 B; lane -> row lane>>3,
//          pos lane&7, fetch global chunk (lane&7)^(lane>>3).
// Fragment (32x32x16): A row = lane&31, k = (lane>>5)*8 + j  -> 16B chunk c = 2*s + (lane>>5)
//          for k-step s (0..3), read at swizzled pos c^(r&7).
// Bank check: 16-lane group covers rows r..r+15 -> (c^(r&7)) cycles all 8 chunk values twice
//          -> 8 x 4-bank groups, 32 banks 2-way (free, m136).
__global__ __launch_bounds__(256, 2) void ca_gemm_bf(
    const unsigned short* __restrict__ Qb,   // [B][SQ][D] bf16
    const unsigned short* __restrict__ Kb,   // [B][SK][D] bf16
    const float* __restrict__ invQ,
    const float* __restrict__ invK,
    const int*   __restrict__ mask,
    float*       __restrict__ out)
{
  __shared__ __align__(16) unsigned short As[BM * BK];   // 16 KB
  __shared__ __align__(16) unsigned short Bs[BN * BK];   // 16 KB

  const int tid  = threadIdx.x;
  const int lane = tid & 63;
  const int w    = tid >> 6;
  const int b    = blockIdx.z;
  const int tm0  = blockIdx.y * BM;
  const int tn0  = blockIdx.x * BN;

  const int srow   = lane >> 3;
  const int gchunk = (lane & 7) ^ srow;

  const char* qrow = (const char*)(Qb + ((size_t)b * SQ + tm0 + w * 32 + srow) * D_) + gchunk * 16;
  const char* krow = (const char*)(Kb + ((size_t)b * SK + tn0 + w * 32 + srow) * D_) + gchunk * 16;
  const size_t rstep8 = (size_t)8 * D_ * 2;   // 8 rows in bytes

  unsigned short* ldsA = &As[(size_t)(w * 32) * BK];
  unsigned short* ldsB = &Bs[(size_t)(w * 32) * BK];

  f32x16 acc[2][2];
  #pragma unroll
  for (int i = 0; i < 2; ++i)
    #pragma unroll
    for (int j = 0; j < 2; ++j)
      #pragma unroll
      for (int r = 0; r < 16; ++r) acc[i][j][r] = 0.0f;

  const int wm = (w >> 1) * 64;
  const int wn = (w & 1) * 64;
  const int ln = lane & 31;    // 32x32 fragment row/col
  const int h  = lane >> 5;    // k-half select

  for (int k0 = 0; k0 < D_; k0 += BK) {
    __syncthreads();   // previous iter's fragment reads done before overwrite
    const size_t kb = (size_t)k0 * 2;
    #pragma unroll
    for (int i = 0; i < 4; ++i)
      async_ld16(qrow + kb + i * rstep8, ldsA + i * 8 * BK);
    #pragma unroll
    for (int i = 0; i < 4; ++i)
      async_ld16(krow + kb + i * rstep8, ldsB + i * 8 * BK);
    __syncthreads();   // compiler drains vmcnt before barrier -> tiles visible

    // Four k-steps of 16 within the 64-wide tile.
    #pragma unroll
    for (int s = 0; s < 4; ++s) {
      const int c = 2 * s + h;      // 16B chunk holding k = s*16 + h*8 .. +7
      const int ra0 = wm + ln, ra1 = wm + 32 + ln;
      const int rb0 = wn + ln, rb1 = wn + 32 + ln;
      short8 a0 = *(const short8*)&As[(size_t)ra0 * BK + (size_t)((c ^ (ra0 & 7)) * 8)];
      short8 a1 = *(const short8*)&As[(size_t)ra1 * BK + (size_t)((c ^ (ra1 & 7)) * 8)];
      short8 b0 = *(const short8*)&Bs[(size_t)rb0 * BK + (size_t)((c ^ (rb0 & 7)) * 8)];
      short8 b1 = *(const short8*)&Bs[(size_t)rb1 * BK + (size_t)((c ^ (rb1 & 7)) * 8)];
      acc[0][0] = __builtin_amdgcn_mfma_f32_32x32x16_bf16(a0, b0, acc[0][0], 0, 0, 0);
      acc[0][1] = __builtin_amdgcn_mfma_f32_32x32x16_bf16(a0, b1, acc[0][1], 0, 0, 0);
      acc[1][0] = __builtin_amdgcn_mfma_f32_32x32x16_bf16(a1, b0, acc[1][0], 0, 0, 0);
      acc[1][1] = __builtin_amdgcn_mfma_f32_32x32x16_bf16(a1, b1, acc[1][1], 0, 0, 0);
    }
  }

  // Epilogue: 32x32 C/D layout col=lane&31, row=(reg&3)+8*(reg>>2)+4*(lane>>5) [m74/m101].
  #pragma unroll
  for (int tj = 0; tj < 2; ++tj) {
    const int gc = tn0 + wn + tj * 32 + ln;
    const int mk = mask[b * SK + gc];
    const float ibv = invK[b * SK + gc];
    #pragma unroll
    for (int ti = 0; ti < 2; ++ti) {
      #pragma unroll
      for (int reg = 0; reg < 16; ++reg) {
        const int row = wm + ti * 32 + (reg & 3) + 8 * (reg >> 2) + 4 * h;
        const float iav = invQ[b * SQ + tm0 + row];
        float v = mk ? acc[ti][tj][reg] * iav * ibv : -1000000000.0f;
        out[((size_t)b * SQ + tm0 + row) * SK + gc] = v;
      }
    }
  }
}

// ---------------- Fallback: single-kernel bf16, LDK=40 ----------------
constexpr int LDK = 40;

__global__ __launch_bounds__(256, 2) void ca_gemm(
    const float* __restrict__ Q, const float* __restrict__ Km,
    const int* __restrict__ mask, float* __restrict__ out)
{
  __shared__ __align__(16) short As[BM * LDK];
  __shared__ __align__(16) short Bs[BN * LDK];
  __shared__ float ssA_part[256];
  __shared__ float ssB_part[256];
  __shared__ float invA[BM];
  __shared__ float invB[BN];

  const int tid  = threadIdx.x;
  const int lane = tid & 63;
  const int w    = tid >> 6;
  const int b    = blockIdx.z;
  const int tm0  = blockIdx.y * BM;
  const int tn0  = blockIdx.x * BN;

  const int ra = tid >> 1;
  const int ka = (tid & 1) * 16;

  const float* qp = Q  + ((size_t)b * SQ + tm0 + ra) * D_ + ka;
  const float* kp = Km + ((size_t)b * SK + tn0 + ra) * D_ + ka;

  f32x4 zero4 = {0.0f, 0.0f, 0.0f, 0.0f};
  f32x4 acc[4][4];
  #pragma unroll
  for (int i = 0; i < 4; ++i)
    #pragma unroll
    for (int j = 0; j < 4; ++j) acc[i][j] = zero4;

  float ssA = 0.0f, ssB = 0.0f;

  const int wm = (w >> 1) * 64;
  const int wn = (w & 1) * 64;
  const int lr = lane & 15;
  const int lq = lane >> 4;

  short* aw = &As[ra * LDK + ka];
  short* bw = &Bs[ra * LDK + ka];

  for (int k0 = 0; k0 < D_; k0 += 32) {
    f32x4 av[4], bv[4];
    #pragma unroll
    for (int i = 0; i < 4; ++i) av[i] = *(const f32x4*)(qp + 4 * i);
    #pragma unroll
    for (int i = 0; i < 4; ++i) bv[i] = *(const f32x4*)(kp + 4 * i);
    qp += 32; kp += 32;

    unsigned pa[8], pb[8];
    #pragma unroll
    for (int i = 0; i < 4; ++i) {
      pa[2*i]   = pack_bf16(av[i].x, av[i].y);
      pa[2*i+1] = pack_bf16(av[i].z, av[i].w);
      pb[2*i]   = pack_bf16(bv[i].x, bv[i].y);
      pb[2*i+1] = pack_bf16(bv[i].z, bv[i].w);
      ssA += av[i].x*av[i].x + av[i].y*av[i].y + av[i].z*av[i].z + av[i].w*av[i].w;
      ssB += bv[i].x*bv[i].x + bv[i].y*bv[i].y + bv[i].z*bv[i].z + bv[i].w*bv[i].w;
    }

    __syncthreads();
    {
      uint4v wa0 = {pa[0], pa[1], pa[2], pa[3]};
      uint4v wa1 = {pa[4], pa[5], pa[6], pa[7]};
      uint4v wb0 = {pb[0], pb[1], pb[2], pb[3]};
      uint4v wb1 = {pb[4], pb[5], pb[6], pb[7]};
      *(uint4v*)(aw)     = wa0;
      *(uint4v*)(aw + 8) = wa1;
      *(uint4v*)(bw)     = wb0;
      *(uint4v*)(bw + 8) = wb1;
    }
    __syncthreads();

    short8 af[4], bf[4];
    #pragma unroll
    for (int t = 0; t < 4; ++t)
      af[t] = *(const short8*)&As[(wm + t * 16 + lr) * LDK + lq * 8];
    #pragma unroll
    for (int t = 0; t < 4; ++t)
      bf[t] = *(const short8*)&Bs[(wn + t * 16 + lr) * LDK + lq * 8];

    #pragma unroll
    for (int i = 0; i < 4; ++i)
      #pragma unroll
      for (int j = 0; j < 4; ++j)
        acc[i][j] = __builtin_amdgcn_mfma_f32_16x16x32_bf16(af[i], bf[j], acc[i][j], 0, 0, 0);
  }

  ssA_part[tid] = ssA;
  ssB_part[tid] = ssB;
  __syncthreads();
  if (tid < BM) {
    float s = ssA_part[2 * tid] + ssA_part[2 * tid + 1];
    invA[tid] = 1.0f / fmaxf(sqrtf(s), 1e-8f);
  } else {
    int r = tid - BM;
    float s = ssB_part[2 * r] + ssB_part[2 * r + 1];
    invB[r] = 1.0f / fmaxf(sqrtf(s), 1e-8f);
  }
  __syncthreads();

  #pragma unroll
  for (int tn = 0; tn < 4; ++tn) {
    const int lc = wn + tn * 16 + lr;
    const int gc = tn0 + lc;
    const int mk = mask[b * SK + gc];
    const float ibv = invB[lc];
    #pragma unroll
    for (int tm = 0; tm < 4; ++tm) {
      const int lrow = wm + tm * 16 + lq * 4;
      #pragma unroll
      for (int r = 0; r < 4; ++r) {
        float v = mk ? acc[tm][tn][r] * invA[lrow + r] * ibv : -1000000000.0f;
        out[((size_t)b * SQ + tm0 + lrow + r) * SK + gc] = v;
      }
    }
  }
}

extern "C" void kernel_launch(void* const* d_in, const int* in_sizes, int n_in,
                              void* d_out, int out_size, void* d_ws, size_t ws_size,
                              hipStream_t stream) {
  const float* Q    = (const float*)d_in[0];
  const float* Km   = (const float*)d_in[1];
  const int*   mask = (const int*)d_in[2];
  float*       out  = (float*)d_out;

  const size_t nQ   = (size_t)B_ * SQ * D_;        // elements
  const size_t nK   = (size_t)B_ * SK * D_;
  const size_t need = (nQ + nK) * 2 + (size_t)B_ * (SQ + SK) * 4;
  if (ws_size >= need) {
    unsigned short* Qb = (unsigned short*)d_ws;
    unsigned short* Kb = Qb + nQ;
    float*          iQ = (float*)(Kb + nK);
    float*          iK = iQ + (size_t)B_ * SQ;
    convert_norm<<<ROWS_T / 4, 256, 0, stream>>>(Q, Km, Qb, Kb, iQ, iK);
    dim3 grid(SK / BN, SQ / BM, B_);
    ca_gemm_bf<<<grid, dim3(256), 0, stream>>>(Qb, Kb, iQ, iK, mask, out);
  } else {
    dim3 grid(SK / BN, SQ / BM, B_);
    ca_gemm<<<grid, dim3(256), 0, stream>>>(Q, Km, mask, out);
  }
}